// Round 4
// baseline (678.272 us; speedup 1.0000x reference)
//
#include <hip/hip_runtime.h>
#include <math.h>

#define B_  8
#define L_  2500
#define D_  512
#define Y_  8921
#define LP  2560    // L padded to 20*128
#define YP  8960    // Y padded to 70*128

typedef _Float16 f16x8 __attribute__((ext_vector_type(8)));
typedef float    f32x4 __attribute__((ext_vector_type(4)));

__device__ __forceinline__ void load_lds16(const _Float16* g, _Float16* l) {
  __builtin_amdgcn_global_load_lds(
      (const __attribute__((address_space(1))) unsigned int*)g,
      (__attribute__((address_space(3))) unsigned int*)l, 16, 0, 0);
}

// ws layout (fp16): X [B_][LP][D_] | U [YP][D_] | F [YP][D_]
__global__ void k_convert(const float* __restrict__ x,
                          const float* __restrict__ Uw,
                          const float* __restrict__ Fw,
                          _Float16* __restrict__ ws,
                          float* __restrict__ loss_slot) {
  if (blockIdx.x == 0 && threadIdx.x == 0) *loss_slot = 0.0f;
  const int NX = B_ * LP * (D_ / 8);   // 1310720
  const int NU = YP * (D_ / 8);        // 573440
  int idx = blockIdx.x * 256 + threadIdx.x;   // one 8-elem slot per thread
  const float* src = nullptr;
  if (idx < NX) {
    int b  = idx / (LP * 64);
    int r  = idx - b * (LP * 64);
    int l  = r >> 6;
    int d8 = r & 63;
    if (l < L_) src = x + (((long)b * L_ + l) * D_ + d8 * 8);
  } else if (idx < NX + NU) {
    int u = idx - NX;
    int y = u >> 6, d8 = u & 63;
    if (y < Y_) src = Uw + ((long)y * D_ + d8 * 8);
  } else {
    int u = idx - NX - NU;
    int y = u >> 6, d8 = u & 63;
    if (y < Y_) src = Fw + ((long)y * D_ + d8 * 8);
  }
  f16x8 o;
  if (src) {
    const float4* s4 = (const float4*)src;
    float4 a = s4[0], c = s4[1];
    o[0] = (_Float16)a.x; o[1] = (_Float16)a.y; o[2] = (_Float16)a.z; o[3] = (_Float16)a.w;
    o[4] = (_Float16)c.x; o[5] = (_Float16)c.y; o[6] = (_Float16)c.z; o[7] = (_Float16)c.w;
  } else {
    for (int i = 0; i < 8; ++i) o[i] = (_Float16)0.0f;
  }
  ((f16x8*)ws)[idx] = o;
}

// Fused: S=U@X^T, C=F@X^T (fp16 MFMA, fp32 acc), per-row sum(exp(S)) and
// sum(exp(S)*C), y = numer/denom + bias.  Pad x rows are exactly zero ->
// each pad column adds exactly 1.0 to den, 0.0 to num; subtract (LP-L_)
// from den at the end (exact under any fragment column permutation).
// Grid: 1D 560 blocks, b = id & 7 pins each batch to one XCD (round-robin
// dispatch) so the 2.6 MB X slice stays L2-resident per XCD.
__global__ __launch_bounds__(256, 2)
void k_attn(const _Float16* __restrict__ ws,
            const float* __restrict__ fb,
            float* __restrict__ out) {
  __shared__ __align__(16) _Float16 UT[128 * 64];
  __shared__ __align__(16) _Float16 FT[128 * 64];
  __shared__ __align__(16) _Float16 XT[128 * 64];
  __shared__ float redD[128], redN[128];

  const int tid  = threadIdx.x;
  const int lane = tid & 63;
  const int wave = tid >> 6;
  const int wy = wave & 1, wl = wave >> 1;
  const int b  = blockIdx.x & 7;    // XCD-pinned batch
  const int yt = blockIdx.x >> 3;

  const _Float16* Xg = ws + (long)b * LP * D_;
  const _Float16* Ug = ws + (long)B_ * LP * D_ + (long)yt * 128 * D_;
  const _Float16* Fg = Ug + (long)YP * D_;

  if (tid < 128) { redD[tid] = 0.0f; redN[tid] = 0.0f; }

  // staging geometry: 16B/lane, 8 lanes/row; fetch XOR-swizzled granule so the
  // lane-linear LDS write yields LDS[r][g] = G[r][g ^ (r&7)]
  const int srow = lane >> 3;
  const int sg8  = ((lane & 7) ^ srow) * 8;

  // compute geometry (16x16x32 frags)
  const int arow = wy * 64 + (lane & 15);
  const int xrow = wl * 64 + (lane & 15);
  const int r7   = lane & 7;
  const int gb   = lane >> 4;

  float denP[4][4], numP[4][4];
  for (int i = 0; i < 4; ++i)
    for (int v = 0; v < 4; ++v) { denP[i][v] = 0.0f; numP[i][v] = 0.0f; }

  for (int lt = 0; lt < LP / 128; ++lt) {
    f32x4 Sacc[4][4], Cacc[4][4];
    for (int mi = 0; mi < 4; ++mi)
      for (int ni = 0; ni < 4; ++ni) {
        f32x4 z = {0.0f, 0.0f, 0.0f, 0.0f};
        Sacc[mi][ni] = z; Cacc[mi][ni] = z;
      }
    for (int kk = 0; kk < D_; kk += 64) {
      __syncthreads();
      for (int c = 0; c < 4; ++c) {
        int row  = wave * 32 + c * 8 + srow;
        int lofs = (wave * 32 + c * 8) * 64;     // wave-uniform LDS chunk base
        long go  = (long)row * D_ + kk + sg8;
        load_lds16(Ug + go, &UT[lofs]);
        load_lds16(Fg + go, &FT[lofs]);
        load_lds16(Xg + (long)lt * 128 * D_ + go, &XT[lofs]);
      }
      __syncthreads();
      for (int ks = 0; ks < 2; ++ks) {
        int off = (((ks * 4 + gb) ^ r7) * 8);    // de-swizzle
        f16x8 au[4], af[4], bx[4];
        for (int mi = 0; mi < 4; ++mi) au[mi] = *(const f16x8*)&UT[(arow + mi * 16) * 64 + off];
        for (int mi = 0; mi < 4; ++mi) af[mi] = *(const f16x8*)&FT[(arow + mi * 16) * 64 + off];
        for (int ni = 0; ni < 4; ++ni) bx[ni] = *(const f16x8*)&XT[(xrow + ni * 16) * 64 + off];
        for (int mi = 0; mi < 4; ++mi)
          for (int ni = 0; ni < 4; ++ni) {
            Sacc[mi][ni] = __builtin_amdgcn_mfma_f32_16x16x32_f16(au[mi], bx[ni], Sacc[mi][ni], 0, 0, 0);
            Cacc[mi][ni] = __builtin_amdgcn_mfma_f32_16x16x32_f16(af[mi], bx[ni], Cacc[mi][ni], 0, 0, 0);
          }
      }
    }
    // epilogue for this L-tile: fold exp into running per-row partials.
    // No masking: pad columns contribute exactly (1.0, 0.0) to (den, num).
    for (int ni = 0; ni < 4; ++ni)
      for (int mi = 0; mi < 4; ++mi)
        for (int v = 0; v < 4; ++v) {
          float e = __expf(Sacc[mi][ni][v]);
          denP[mi][v] += e;
          numP[mi][v] += e * Cacc[mi][ni][v];
        }
  }

  // reduce across the 16 lanes (lane bits 0..3) that share each y row
  for (int m = 1; m < 16; m <<= 1)
    for (int mi = 0; mi < 4; ++mi)
      for (int v = 0; v < 4; ++v) {
        denP[mi][v] += __shfl_xor(denP[mi][v], m, 64);
        numP[mi][v] += __shfl_xor(numP[mi][v], m, 64);
      }

  __syncthreads();
  if ((lane & 15) == 0) {
    for (int mi = 0; mi < 4; ++mi)
      for (int v = 0; v < 4; ++v) {
        int yl = wy * 64 + mi * 16 + gb * 4 + v;
        atomicAdd(&redD[yl], denP[mi][v]);
        atomicAdd(&redN[yl], numP[mi][v]);
      }
  }
  __syncthreads();
  if (tid < 128) {
    int yg = yt * 128 + tid;
    if (yg < Y_)
      out[(long)b * Y_ + yg] = redN[tid] / (redD[tid] - (float)(LP - L_)) + fb[yg];
  }
}

__global__ void k_loss(const float* __restrict__ y,
                       const float* __restrict__ t,
                       float* __restrict__ loss) {
  float p = 0.0f;
  for (int i = blockIdx.x * 256 + threadIdx.x; i < B_ * Y_; i += gridDim.x * 256) {
    float v = y[i], tg = t[i];
    p += fmaxf(v, 0.0f) - v * tg + log1pf(__expf(-fabsf(v)));
  }
  for (int m = 32; m; m >>= 1) p += __shfl_down(p, m, 64);
  __shared__ float wsum[4];
  int lane = threadIdx.x & 63, wv = threadIdx.x >> 6;
  if (lane == 0) wsum[wv] = p;
  __syncthreads();
  if (threadIdx.x == 0) {
    float s = wsum[0] + wsum[1] + wsum[2] + wsum[3];
    atomicAdd(loss, s * (1.0f / (float)(B_ * Y_)));
  }
}

extern "C" void kernel_launch(void* const* d_in, const int* in_sizes, int n_in,
                              void* d_out, int out_size, void* d_ws, size_t ws_size,
                              hipStream_t stream) {
  (void)in_sizes; (void)n_in; (void)out_size; (void)ws_size;
  const float* x       = (const float*)d_in[0];
  const float* target  = (const float*)d_in[1];
  const float* U_w     = (const float*)d_in[3];
  const float* final_w = (const float*)d_in[4];
  const float* final_b = (const float*)d_in[5];
  float* out = (float*)d_out;
  _Float16* ws = (_Float16*)d_ws;

  // total 8-elem slots: B_*LP*D_/8 + 2*YP*D_/8 = 2457600 -> 9600 blocks
  k_convert<<<9600, 256, 0, stream>>>(x, U_w, final_w, ws, out + B_ * Y_);

  // 1D grid: blockIdx.x & 7 = batch (XCD-pinned), >>3 = y-tile
  k_attn<<<(YP / 128) * B_, 256, 0, stream>>>(ws, final_b, out);

  k_loss<<<140, 256, 0, stream>>>(out, target, out + B_ * Y_);
}

// Round 5
// 592.000 us; speedup vs baseline: 1.1457x; 1.1457x over previous
//
#include <hip/hip_runtime.h>
#include <math.h>

#define B_  8
#define L_  2500
#define D_  512
#define Y_  8921
#define LP  2560    // L padded to 10*256
#define YP  8960    // Y padded to 70*128

// ws layout: fp16 X[B_][LP][D_] | U[YP][D_] | F[YP][D_]  (19,660,800 halves)
// then fp32  denG[B_][YP] | numG[B_][YP]                 (143,360 floats)
#define WS_F16_HALVES  (B_ * LP * D_ + 2 * YP * D_)
#define ACC_FLOATS     (2 * B_ * YP)

typedef _Float16 f16x8 __attribute__((ext_vector_type(8)));
typedef float    f32x4 __attribute__((ext_vector_type(4)));

__device__ __forceinline__ void load_lds16(const _Float16* g, _Float16* l) {
  __builtin_amdgcn_global_load_lds(
      (const __attribute__((address_space(1))) unsigned int*)g,
      (__attribute__((address_space(3))) unsigned int*)l, 16, 0, 0);
}

__global__ void k_convert(const float* __restrict__ x,
                          const float* __restrict__ Uw,
                          const float* __restrict__ Fw,
                          _Float16* __restrict__ ws,
                          float* __restrict__ loss_slot) {
  if (blockIdx.x == 0 && threadIdx.x == 0) *loss_slot = 0.0f;
  const int NX = B_ * LP * (D_ / 8);   // 1310720
  const int NU = YP * (D_ / 8);        // 573440
  int idx = blockIdx.x * 256 + threadIdx.x;   // one 8-elem slot per thread
  // zero the global den/num accumulators (ws is poisoned before every launch)
  if (idx < ACC_FLOATS) ((float*)(ws + WS_F16_HALVES))[idx] = 0.0f;
  const float* src = nullptr;
  if (idx < NX) {
    int b  = idx / (LP * 64);
    int r  = idx - b * (LP * 64);
    int l  = r >> 6;
    int d8 = r & 63;
    if (l < L_) src = x + (((long)b * L_ + l) * D_ + d8 * 8);
  } else if (idx < NX + NU) {
    int u = idx - NX;
    int y = u >> 6, d8 = u & 63;
    if (y < Y_) src = Uw + ((long)y * D_ + d8 * 8);
  } else {
    int u = idx - NX - NU;
    int y = u >> 6, d8 = u & 63;
    if (y < Y_) src = Fw + ((long)y * D_ + d8 * 8);
  }
  f16x8 o;
  if (src) {
    const float4* s4 = (const float4*)src;
    float4 a = s4[0], c = s4[1];
    o[0] = (_Float16)a.x; o[1] = (_Float16)a.y; o[2] = (_Float16)a.z; o[3] = (_Float16)a.w;
    o[4] = (_Float16)c.x; o[5] = (_Float16)c.y; o[6] = (_Float16)c.z; o[7] = (_Float16)c.w;
  } else {
    for (int i = 0; i < 8; ++i) o[i] = (_Float16)0.0f;
  }
  ((f16x8*)ws)[idx] = o;
}

// Fused dual-GEMM + softmax-weighted reduction, 128y x 256l tile, 8 waves
// (wy in {0,1} x wl in {0..3}), BK=64, XOR-swizzled LDS via global_load_lds.
// Each (yt,b) is split into 2 L-halves across blocks; per-row partial
// sum(exp(S)) / sum(exp(S)*C) are atomically added to global fp32 buffers.
// Pad x rows are exactly zero -> pad columns contribute exactly (1,0);
// k_final subtracts (LP-L_) from den. Exact under any fragment permutation.
__global__ __launch_bounds__(512, 2)
void k_attn(const _Float16* __restrict__ ws,
            float* __restrict__ accG) {
  __shared__ __align__(16) _Float16 TILE[32768];   // U(8192) | F(8192) | X(16384)

  const int tid  = threadIdx.x;
  const int lane = tid & 63;
  const int wave = tid >> 6;          // 0..7
  const int wy = wave & 1, wl = wave >> 1;
  const int yt = blockIdx.x;          // 0..69  (fast dim, as in round 3)
  const int b  = blockIdx.y;          // 0..7
  const int lh = blockIdx.z;          // 0..1 L-half

  const _Float16* Xg = ws + (long)b * LP * D_ + (long)lh * (LP / 2) * D_;
  const _Float16* Ug = ws + (long)B_ * LP * D_ + (long)yt * 128 * D_;
  const _Float16* Fg = Ug + (long)YP * D_;

  // staging geometry: 16B/lane, 8 lanes/row, 8 rows/segment (1KB)
  const int srow = lane >> 3;                 // row within segment
  const int sg8  = ((lane & 7) ^ srow) * 8;   // XOR-swizzled granule

  // compute geometry
  const int arow = wy * 64 + (lane & 15);     // U/F row in [0,128)
  const int xrow = wl * 64 + (lane & 15);     // X row in [0,256)
  const int r7   = lane & 7;
  const int gb   = lane >> 4;

  _Float16* UT = TILE;
  _Float16* FT = TILE + 8192;
  _Float16* XT = TILE + 16384;

  float denP[4][4], numP[4][4];
  for (int i = 0; i < 4; ++i)
    for (int v = 0; v < 4; ++v) { denP[i][v] = 0.0f; numP[i][v] = 0.0f; }

  for (int lt = 0; lt < 5; ++lt) {
    f32x4 Sacc[4][4], Cacc[4][4];
    for (int mi = 0; mi < 4; ++mi)
      for (int ni = 0; ni < 4; ++ni) {
        f32x4 z = {0.0f, 0.0f, 0.0f, 0.0f};
        Sacc[mi][ni] = z; Cacc[mi][ni] = z;
      }
    const _Float16* Xt = Xg + (long)lt * 256 * D_;
    for (int kk = 0; kk < D_; kk += 64) {
      __syncthreads();
      for (int i = 0; i < 8; ++i) {
        int seg = wave * 8 + i;                      // wave-uniform
        const _Float16* g;
        if (seg < 16)      g = Ug + (long)(seg * 8 + srow) * D_;
        else if (seg < 32) g = Fg + (long)((seg - 16) * 8 + srow) * D_;
        else               g = Xt + (long)((seg - 32) * 8 + srow) * D_;
        load_lds16(g + kk + sg8, TILE + seg * 512);
      }
      __syncthreads();
      for (int ks = 0; ks < 2; ++ks) {
        int off = (((ks * 4 + gb) ^ r7) * 8);        // de-swizzle
        f16x8 au[4], af[4], bx[4];
        for (int mi = 0; mi < 4; ++mi) au[mi] = *(const f16x8*)&UT[(arow + mi * 16) * 64 + off];
        for (int mi = 0; mi < 4; ++mi) af[mi] = *(const f16x8*)&FT[(arow + mi * 16) * 64 + off];
        for (int ni = 0; ni < 4; ++ni) bx[ni] = *(const f16x8*)&XT[(xrow + ni * 16) * 64 + off];
        for (int mi = 0; mi < 4; ++mi)
          for (int ni = 0; ni < 4; ++ni) {
            Sacc[mi][ni] = __builtin_amdgcn_mfma_f32_16x16x32_f16(au[mi], bx[ni], Sacc[mi][ni], 0, 0, 0);
            Cacc[mi][ni] = __builtin_amdgcn_mfma_f32_16x16x32_f16(af[mi], bx[ni], Cacc[mi][ni], 0, 0, 0);
          }
      }
    }
    // fold exp into running per-row partials (no L mask needed)
    for (int ni = 0; ni < 4; ++ni)
      for (int mi = 0; mi < 4; ++mi)
        for (int v = 0; v < 4; ++v) {
          float e = __expf(Sacc[mi][ni][v]);
          denP[mi][v] += e;
          numP[mi][v] += e * Cacc[mi][ni][v];
        }
  }

  // reduce across the 16 lanes sharing each y row, then global atomics
  for (int m = 1; m < 16; m <<= 1)
    for (int mi = 0; mi < 4; ++mi)
      for (int v = 0; v < 4; ++v) {
        denP[mi][v] += __shfl_xor(denP[mi][v], m, 64);
        numP[mi][v] += __shfl_xor(numP[mi][v], m, 64);
      }
  if ((lane & 15) == 0) {
    float* denG = accG;
    float* numG = accG + B_ * YP;
    for (int mi = 0; mi < 4; ++mi)
      for (int v = 0; v < 4; ++v) {
        int y = yt * 128 + wy * 64 + mi * 16 + gb * 4 + v;
        atomicAdd(&denG[b * YP + y], denP[mi][v]);
        atomicAdd(&numG[b * YP + y], numP[mi][v]);
      }
  }
}

__global__ void k_final(const float* __restrict__ accG,
                        const float* __restrict__ fb,
                        float* __restrict__ out) {
  int id = blockIdx.x * 256 + threadIdx.x;
  if (id >= B_ * Y_) return;
  int b = id / Y_, y = id - b * Y_;
  const float* denG = accG;
  const float* numG = accG + B_ * YP;
  float den = denG[b * YP + y] - (float)(LP - L_);
  out[id] = numG[b * YP + y] / den + fb[y];
}

__global__ void k_loss(const float* __restrict__ y,
                       const float* __restrict__ t,
                       float* __restrict__ loss) {
  float p = 0.0f;
  for (int i = blockIdx.x * 256 + threadIdx.x; i < B_ * Y_; i += gridDim.x * 256) {
    float v = y[i], tg = t[i];
    p += fmaxf(v, 0.0f) - v * tg + log1pf(__expf(-fabsf(v)));
  }
  for (int m = 32; m; m >>= 1) p += __shfl_down(p, m, 64);
  __shared__ float wsum[4];
  int lane = threadIdx.x & 63, wv = threadIdx.x >> 6;
  if (lane == 0) wsum[wv] = p;
  __syncthreads();
  if (threadIdx.x == 0) {
    float s = wsum[0] + wsum[1] + wsum[2] + wsum[3];
    atomicAdd(loss, s * (1.0f / (float)(B_ * Y_)));
  }
}

extern "C" void kernel_launch(void* const* d_in, const int* in_sizes, int n_in,
                              void* d_out, int out_size, void* d_ws, size_t ws_size,
                              hipStream_t stream) {
  (void)in_sizes; (void)n_in; (void)out_size; (void)ws_size;
  const float* x       = (const float*)d_in[0];
  const float* target  = (const float*)d_in[1];
  const float* U_w     = (const float*)d_in[3];
  const float* final_w = (const float*)d_in[4];
  const float* final_b = (const float*)d_in[5];
  float* out = (float*)d_out;
  _Float16* ws = (_Float16*)d_ws;
  float* accG = (float*)(ws + WS_F16_HALVES);

  k_convert<<<9600, 256, 0, stream>>>(x, U_w, final_w, ws, out + B_ * Y_);

  dim3 g(YP / 128, B_, 2);
  k_attn<<<g, 512, 0, stream>>>(ws, accG);

  k_final<<<(B_ * Y_ + 255) / 256, 256, 0, stream>>>(accG, final_b, out);
  k_loss<<<140, 256, 0, stream>>>(out, target, out + B_ * Y_);
}